// Round 1
// baseline (649.024 us; speedup 1.0000x reference)
//
#include <hip/hip_runtime.h>
#include <math.h>

#define BB 512   // batch
#define TT 1024  // max seq len
#define HH 128   // hidden

// ---------------------------------------------------------------------------
// Kernel 1: bitonic sort of (length, idx) composite keys, descending.
// Produces a permutation `order` such that lengths[order[0]] >= ... .
// Only affects load balance; any permutation is still CORRECT.
// ---------------------------------------------------------------------------
__global__ __launch_bounds__(512) void sort_kernel(const int* __restrict__ lengths,
                                                   int* __restrict__ order) {
  __shared__ int comp[BB];
  const int t = threadIdx.x;
  // len in [1,1024] -> 11 bits; idx in [0,512) -> 9 bits. Unique keys => deterministic.
  comp[t] = (lengths[t] << 9) | t;
  __syncthreads();
  for (int k = 2; k <= BB; k <<= 1) {
    for (int j = k >> 1; j > 0; j >>= 1) {
      int ixj = t ^ j;
      if (ixj > t) {
        int a = comp[t], b = comp[ixj];
        bool descBlock = ((t & k) == 0);
        bool doSwap = descBlock ? (a < b) : (a > b);
        if (doSwap) { comp[t] = b; comp[ixj] = a; }
      }
      __syncthreads();
    }
  }
  order[t] = comp[t] & 511;
}

// ---------------------------------------------------------------------------
// Kernel 2: GRU recurrence. 256 blocks x 512 threads; block j processes
// batches order[j] and order[511-j] sequentially (antithetic pairing =>
// every block does ~1025 total steps).
//
// Per step:
//   phase 1 (all 512 threads): thread (i = tid&127, kc = tid>>7) computes
//     partial dot products of h[32*kc .. 32*kc+32) with w_hh rows i, 128+i,
//     256+i (weights register-resident: 96 VGPRs, loaded once).
//   phase 2 (threads 0..127): reduce 4 partials per gate, add fused gx
//     (IN=2 so it's 6 FMAs), sigmoid/tanh, update h in LDS.
// ---------------------------------------------------------------------------
__global__ __launch_bounds__(512, 2) void gru_main(
    const float* __restrict__ x, const int* __restrict__ lengths,
    const float* __restrict__ w_ih, const float* __restrict__ w_hh,
    const float* __restrict__ b_ih, const float* __restrict__ b_hh,
    const float* __restrict__ head_w, const float* __restrict__ head_b,
    const int* __restrict__ order, float* __restrict__ out) {
  __shared__ __align__(16) float hs[HH];        // current hidden state
  __shared__ float parts[3][4][HH];             // split-K partials
  __shared__ __align__(16) float xrow[TT * 2];  // staged x row (8 KB)
  // Padding to push LDS use past 80KB so only ONE block fits per CU:
  // guarantees the 256 sorted-balanced blocks spread 1:1 over 256 CUs.
  __shared__ float lds_pad[17000];              // 68 KB

  const int tid = threadIdx.x;
  const int i  = tid & (HH - 1);  // output row within a gate
  const int kc = tid >> 7;        // k-chunk 0..3 (32 h-elements each)

  // --- one-time: weights into registers ---
  float4 wv[3][8];  // wv[g][q] = w_hh[g*128 + i][kc*32 + 4q .. +3]
#pragma unroll
  for (int g = 0; g < 3; ++g)
#pragma unroll
    for (int q = 0; q < 8; ++q)
      wv[g][q] = *reinterpret_cast<const float4*>(
          &w_hh[(g * HH + i) * HH + kc * 32 + q * 4]);

  float wi0[3], wi1[3], bi[3], bh[3];
#pragma unroll
  for (int g = 0; g < 3; ++g) {
    wi0[g] = w_ih[(g * HH + i) * 2 + 0];
    wi1[g] = w_ih[(g * HH + i) * 2 + 1];
    bi[g] = b_ih[g * HH + i];
    bh[g] = b_hh[g * HH + i];
  }
  const float hw = head_w[i];
  const float hb = head_b[0];

  for (int pb = 0; pb < 2; ++pb) {
    const int slot = pb ? (BB - 1 - (int)blockIdx.x) : (int)blockIdx.x;
    const int b = order[slot];
    const int len = lengths[b];  // in [1, 1024]

    if (len == 0) lds_pad[tid] = 1.0f;  // never true; keeps pad allocated

    // stage this batch's x row (coalesced) + init h
    for (int ofs = tid; ofs < len * 2; ofs += 512)
      xrow[ofs] = x[(size_t)b * (TT * 2) + ofs];
    if (tid < HH) hs[tid] = 0.0f;
    __syncthreads();

    for (int t = 0; t < len; ++t) {
      // ---- phase 1: split-K matvec, all threads ----
      float4 h4[8];
#pragma unroll
      for (int q = 0; q < 8; ++q)
        h4[q] = *reinterpret_cast<const float4*>(&hs[kc * 32 + q * 4]);
      float pr = 0.f, pz = 0.f, pn = 0.f;
#pragma unroll
      for (int q = 0; q < 8; ++q) {
        pr += wv[0][q].x * h4[q].x; pr += wv[0][q].y * h4[q].y;
        pr += wv[0][q].z * h4[q].z; pr += wv[0][q].w * h4[q].w;
        pz += wv[1][q].x * h4[q].x; pz += wv[1][q].y * h4[q].y;
        pz += wv[1][q].z * h4[q].z; pz += wv[1][q].w * h4[q].w;
        pn += wv[2][q].x * h4[q].x; pn += wv[2][q].y * h4[q].y;
        pn += wv[2][q].z * h4[q].z; pn += wv[2][q].w * h4[q].w;
      }
      parts[0][kc][i] = pr;
      parts[1][kc][i] = pz;
      parts[2][kc][i] = pn;
      __syncthreads();

      // ---- phase 2: reduce + gates + h update, threads 0..127 ----
      if (tid < HH) {
        float gr = bh[0] + parts[0][0][tid] + parts[0][1][tid] +
                   parts[0][2][tid] + parts[0][3][tid];
        float gz = bh[1] + parts[1][0][tid] + parts[1][1][tid] +
                   parts[1][2][tid] + parts[1][3][tid];
        float gn = bh[2] + parts[2][0][tid] + parts[2][1][tid] +
                   parts[2][2][tid] + parts[2][3][tid];
        const float x0 = xrow[t * 2 + 0];
        const float x1 = xrow[t * 2 + 1];
        const float ar = bi[0] + x0 * wi0[0] + x1 * wi1[0] + gr;
        const float az = bi[1] + x0 * wi0[1] + x1 * wi1[1] + gz;
        const float an = bi[2] + x0 * wi0[2] + x1 * wi1[2];
        const float r = 1.0f / (1.0f + __expf(-ar));
        const float z = 1.0f / (1.0f + __expf(-az));
        const float a = an + r * gn;          // tanh argument
        const float e2 = __expf(-2.0f * a);   // |a| < ~15 -> no overflow
        const float n = (1.0f - e2) / (1.0f + e2);
        hs[tid] = (1.0f - z) * n + z * hs[tid];
      }
      __syncthreads();
    }

    // ---- head: out[b] = dot(h, head_w) + head_b ----
    if (tid < HH) parts[0][0][tid] = hs[tid] * hw;
    __syncthreads();
    if (tid == 0) {
      float s = hb;
      for (int q = 0; q < HH; ++q) s += parts[0][0][q];
      out[b] = s;
    }
    __syncthreads();  // protect hs/parts before next batch reuses them
  }
}

extern "C" void kernel_launch(void* const* d_in, const int* in_sizes, int n_in,
                              void* d_out, int out_size, void* d_ws, size_t ws_size,
                              hipStream_t stream) {
  const float* x      = (const float*)d_in[0];
  const int*   lengths = (const int*)d_in[1];
  const float* w_ih   = (const float*)d_in[2];
  const float* w_hh   = (const float*)d_in[3];
  const float* b_ih   = (const float*)d_in[4];
  const float* b_hh   = (const float*)d_in[5];
  const float* head_w = (const float*)d_in[6];
  const float* head_b = (const float*)d_in[7];
  float* out = (float*)d_out;
  int* order = (int*)d_ws;  // 512 ints of scratch

  sort_kernel<<<1, 512, 0, stream>>>(lengths, order);
  gru_main<<<256, 512, 0, stream>>>(x, lengths, w_ih, w_hh, b_ih, b_hh,
                                    head_w, head_b, order, out);
}